// Round 5
// baseline (213.562 us; speedup 1.0000x reference)
//
#include <hip/hip_runtime.h>

#define LN_EPS 1e-5f

typedef __attribute__((ext_vector_type(8))) short s8vec;   // 8 bf16 (MFMA A/B frag)
typedef __attribute__((ext_vector_type(4))) float f4vec;   // MFMA C/D frag

// ---- workspace layout (bytes) ----
#define OFF_WPT   0u         // gamma-folded W_projT, PRE-SWIZZLED [12 chunks][256 n][128 B]
#define OFF_W1T   393216u    // W1T, LINEAR [256 e][256 d] bf16 (k1b direct-loads frags)
#define OFF_U     524288u    // u[256] f32 : sum_k gamma_k W[k][d]
#define OFF_C     525312u    // c[256] f32 : sum_k beta_k W[k][d] + b_proj[d]
#define OFF_UPART 526336u    // 48*256 f32 partials
#define OFF_VPART 575488u
#define OFF_PM    624640u    // per-chunk softmax max   [2048] f32
#define OFF_PS    632832u    // per-chunk softmax denom [2048] f32
#define OFF_PO    641024u    // per-chunk weighted sums [2048][256] f32
#define OFF_H     3145728u   // h bf16 [131072 rows][256] = 64 MB

#define BAR()     asm volatile("s_barrier" ::: "memory")
#define WAIT_V4() asm volatile("s_waitcnt vmcnt(4) lgkmcnt(0)" ::: "memory")
#define WAIT_V0() asm volatile("s_waitcnt vmcnt(0) lgkmcnt(0)" ::: "memory")
#define WAIT_L0() asm volatile("s_waitcnt lgkmcnt(0)" ::: "memory")
// Pin issue order so counted vmcnt is valid: gll16s must stay the OLDEST
// outstanding vmem ops (round-3 lesson).
#define ORDER_FENCE() do { asm volatile("" ::: "memory"); \
                           __builtin_amdgcn_sched_barrier(0); } while (0)

__device__ __forceinline__ unsigned short f2bf(float f) {  // RNE fp32->bf16 (finite inputs)
  unsigned int u = __float_as_uint(f);
  u += 0x7fffu + ((u >> 16) & 1u);
  return (unsigned short)(u >> 16);
}
__device__ __forceinline__ float bf2f(unsigned short h) {
  return __uint_as_float(((unsigned int)h) << 16);
}
__device__ __forceinline__ void gll16(const void* g, void* l) {  // async global->LDS, 16 B/lane
  __builtin_amdgcn_global_load_lds(
      (const __attribute__((address_space(1))) unsigned int*)g,
      (__attribute__((address_space(3))) unsigned int*)l, 16, 0, 0);
}

// K0: fold gamma into W_proj, transpose, store PRE-INVERSE-SWIZZLED (for k1a's
// linear global_load_lds staging). W1T stored LINEAR (k1b reads frags direct).
__global__ void k0_prep(const float* __restrict__ Wp,
                        const float* __restrict__ gamma,
                        const float* __restrict__ beta,
                        const float* __restrict__ W1,
                        char* __restrict__ ws) {
  const int blk = blockIdx.x;
  const int n = threadIdx.x;
  const int sw = (n & 7) << 4;
  if (blk < 48) {
    unsigned short* wpt = (unsigned short*)(ws + OFF_WPT);
    const int k0 = blk * 16;
    float up = 0.f, vp = 0.f;
#pragma unroll
    for (int j = 0; j < 16; ++j) {
      const int k = k0 + j;
      const float w = Wp[k * 256 + n];          // coalesced across n
      const float wpv = gamma[k] * w;
      up += wpv;
      vp += beta[k] * w;
      const int c = k >> 6, kc = k & 63;
      wpt[c * 16384 + n * 64 + ((((kc * 2) ^ sw)) >> 1)] = f2bf(wpv);
    }
    ((float*)(ws + OFF_UPART))[blk * 256 + n] = up;
    ((float*)(ws + OFF_VPART))[blk * 256 + n] = vp;
  } else {
    unsigned short* w1t = (unsigned short*)(ws + OFF_W1T);
    const int d0 = (blk - 48) * 16;
#pragma unroll
    for (int j = 0; j < 16; ++j) {
      const int d = d0 + j;
      w1t[n * 256 + d] = f2bf(W1[d * 256 + n]); // W1T[e][d] = W1[d][e], linear
    }
  }
}

__global__ void k0_reduce(const float* __restrict__ bproj, char* __restrict__ ws) {
  const int n = threadIdx.x;
  const float* upart = (const float*)(ws + OFF_UPART);
  const float* vpart = (const float*)(ws + OFF_VPART);
  float u = 0.f, v = 0.f;
  for (int i = 0; i < 48; ++i) {
    u += upart[i * 256 + n];
    v += vpart[i * 256 + n];
  }
  ((float*)(ws + OFF_U))[n] = u;
  ((float*)(ws + OFF_C))[n] = v + bproj[n];
}

// K1a: LN + projection, h -> ws (bf16). Per wave = 16 rows; A-frags built in
// registers straight from the x stream (no LDS for A). Only B staged in LDS.
// 35 KB LDS -> 3 blocks/CU.
__global__ __launch_bounds__(256, 3)
void k1a_proj(const float* __restrict__ x, char* __restrict__ ws) {
  __shared__ __align__(16) char sm_b[32768];   // W'T chunk bf16 [256][64], XOR-swizzled
  __shared__ float sm_u[256], sm_c[256];
  __shared__ float sm_mu[64], sm_inv[64];

  const int tid  = threadIdx.x;
  const int lane = tid & 63;
  const int wid  = tid >> 6;                   // wave owns rows wid*16..+16
  const int lr = lane & 15;
  const int lq = lane >> 4;

  sm_u[tid] = ((const float*)(ws + OFF_U))[tid];
  sm_c[tid] = ((const float*)(ws + OFF_C))[tid];

  // lane's x slice: row = wid*16+lr, k base = lq*8 (A-frag layout directly)
  const float* xrow = x + (size_t)(blockIdx.x * 64 + wid * 16 + lr) * 768 + lq * 8;
  const char* bsrc = (const char*)ws + OFF_WPT + wid * 8192 + lane * 16;
  char*       bdst = sm_b + wid * 8192 + lane * 16;

  const f4vec fz = {0.f, 0.f, 0.f, 0.f};
  f4vec acc[16];
#pragma unroll
  for (int n = 0; n < 16; ++n) acc[n] = fz;

  float s1 = 0.f, s2 = 0.f;
  float4 xc[4];                                // chunk c: 2 ks * 8 floats
#pragma unroll
  for (int q = 0; q < 4; ++q)
    xc[q] = *(const float4*)(xrow + (q >> 1) * 32 + (q & 1) * 4);

  for (int c = 0; c < 12; ++c) {
    // B: async linear copy of pre-swizzled W'T chunk (L2-resident)
#pragma unroll
    for (int s = 0; s < 8; ++s) gll16(bsrc + c * 32768 + s * 1024, bdst + s * 1024);
    ORDER_FENCE();                             // gll16s stay oldest outstanding
    // A: sanitize, LN sums, pack bf16 frags IN REGISTERS (consumes xc)
    s8vec af[2];
#pragma unroll
    for (int ks = 0; ks < 2; ++ks) {
      float v[8];
#pragma unroll
      for (int j = 0; j < 4; ++j) { v[j] = ((const float*)&xc[ks*2])[j];
                                    v[4+j] = ((const float*)&xc[ks*2+1])[j]; }
      unsigned int pk[4];
#pragma unroll
      for (int j = 0; j < 8; ++j) {
        float f = v[j];
        if ((__float_as_uint(f) & 0x7f800000u) == 0x7f800000u) f = 0.f;  // nan/inf->0
        s1 += f; s2 += f * f;
        const unsigned int hb = f2bf(f);
        if ((j & 1) == 0) pk[j >> 1] = hb; else pk[j >> 1] |= hb << 16;
      }
      af[ks] = *(s8vec*)pk;
    }
    // prefetch chunk c+1 into the now-free xc regs (stays in flight across BAR)
    if (c < 11) {
#pragma unroll
      for (int q = 0; q < 4; ++q)
        xc[q] = *(const float4*)(xrow + (c + 1) * 64 + (q >> 1) * 32 + (q & 1) * 4);
    }
    if (c < 11) WAIT_V4(); else WAIT_V0();     // drain gll16s; x prefetch flying
    BAR();
    // MFMA: 16 rows x 256 cols, 2 k-steps of 32
#pragma unroll
    for (int ks = 0; ks < 2; ++ks) {
      const int kb = (ks * 32 + lq * 8) * 2;
#pragma unroll
      for (int n = 0; n < 16; ++n) {
        const int row = n * 16 + lr;
        const s8vec bf = *(const s8vec*)(sm_b + ((row * 128 + kb) ^ ((row & 7) << 4)));
        acc[n] = __builtin_amdgcn_mfma_f32_16x16x32_bf16(af[ks], bf, acc[n], 0, 0, 0);
      }
    }
    BAR();                                     // reads retired before next staging
  }

  // ---- LN row stats: reduce across the 4 lq-groups of each row ----
  s1 += __shfl_xor(s1, 16); s1 += __shfl_xor(s1, 32);
  s2 += __shfl_xor(s2, 16); s2 += __shfl_xor(s2, 32);
  {
    const float mu = s1 * (1.f / 768.f);
    float var = s2 * (1.f / 768.f) - mu * mu;
    var = fmaxf(var, 0.f);
    if (lane < 16) {                           // lq==0 lanes hold rows wid*16+lr
      sm_mu[wid * 16 + lr]  = mu;
      sm_inv[wid * 16 + lr] = rsqrtf(var + LN_EPS);
    }
  }
  WAIT_L0();                                   // wave-local RAW on sm_mu/sm_inv

  // ---- finalize h, pack pairs via shfl, coalesced b32 global stores ----
  unsigned int* hout = (unsigned int*)(ws + OFF_H) + (size_t)blockIdx.x * 64 * 128;
  const int odd = lane & 1;
  float muv[4], invv[4];
#pragma unroll
  for (int i = 0; i < 4; ++i) {
    muv[i]  = sm_mu[wid * 16 + lq * 4 + i];
    invv[i] = sm_inv[wid * 16 + lq * 4 + i];
  }
#pragma unroll
  for (int n = 0; n < 16; ++n) {
    const int cd = n * 16 + lr;
    const float uv = sm_u[cd], cv = sm_c[cd];
    float hv[4];
#pragma unroll
    for (int i = 0; i < 4; ++i)
      hv[i] = invv[i] * (acc[n][i] - muv[i] * uv) + cv;
#pragma unroll
    for (int i = 0; i < 4; ++i) {
      const float hp = __shfl_xor(hv[i], 1);   // partner col of the pair
      if ((i >> 1) == odd) {                   // even lane: i=0,1; odd: i=2,3
        const unsigned int lo = odd ? f2bf(hp) : f2bf(hv[i]);
        const unsigned int hi = odd ? f2bf(hv[i]) : f2bf(hp);
        hout[(wid * 16 + lq * 4 + i) * 128 + n * 8 + (lr >> 1)] = lo | (hi << 16);
      }
    }
  }
}

// K1b: a = tanh(h@W1 + b1), logits, chunk softmax + pooling partials.
// No big LDS: h (L1/L2-hot) and W1T (L2-resident) frags loaded direct.
__global__ __launch_bounds__(256, 3)
void k1b_mlp(const float* __restrict__ b1,
             const float* __restrict__ W2,
             char* __restrict__ ws) {
  __shared__ float sm_lp[64 * 4];
  __shared__ float sm_lg[64];
  __shared__ float sm_e[64];

  const int tid  = threadIdx.x;
  const int lane = tid & 63;
  const int wid  = tid >> 6;                   // wave owns e-quadrant wid*64..+64
  const int lr = lane & 15;
  const int lq = lane >> 4;

  const unsigned short* hb  = (const unsigned short*)(ws + OFF_H) +
                              (size_t)blockIdx.x * 64 * 256;
  const unsigned short* w1t = (const unsigned short*)(ws + OFF_W1T);

  float b1v[4], w2v[4];
#pragma unroll
  for (int n = 0; n < 4; ++n) {
    const int e = wid * 64 + n * 16 + lr;
    b1v[n] = b1[e]; w2v[n] = W2[e];
  }

  const f4vec fz = {0.f, 0.f, 0.f, 0.f};
  f4vec acc2[4][4];
#pragma unroll
  for (int m = 0; m < 4; ++m)
#pragma unroll
    for (int n = 0; n < 4; ++n) acc2[m][n] = fz;

#pragma unroll
  for (int ks = 0; ks < 8; ++ks) {             // k = d, 8 steps of 32
    s8vec af[4], bf[4];
#pragma unroll
    for (int m = 0; m < 4; ++m)
      af[m] = *(const s8vec*)(hb + (m * 16 + lr) * 256 + ks * 32 + lq * 8);
#pragma unroll
    for (int n = 0; n < 4; ++n)
      bf[n] = *(const s8vec*)(w1t + (wid * 64 + n * 16 + lr) * 256 + ks * 32 + lq * 8);
#pragma unroll
    for (int m = 0; m < 4; ++m)
#pragma unroll
      for (int n = 0; n < 4; ++n)
        acc2[m][n] = __builtin_amdgcn_mfma_f32_16x16x32_bf16(af[m], bf[n], acc2[m][n], 0, 0, 0);
  }

  float lp[4][4];
#pragma unroll
  for (int m = 0; m < 4; ++m)
#pragma unroll
    for (int i = 0; i < 4; ++i) lp[m][i] = 0.f;

#pragma unroll
  for (int m = 0; m < 4; ++m) {
#pragma unroll
    for (int n = 0; n < 4; ++n) {
      const float b1n = b1v[n], w2n = w2v[n];
#pragma unroll
      for (int i = 0; i < 4; ++i) {
        float z = acc2[m][n][i] + b1n;
        z = fminf(fmaxf(z, -15.f), 15.f);
        const float e2 = __expf(2.f * z);
        const float a = (e2 - 1.f) / (e2 + 1.f);   // tanh
        lp[m][i] += a * w2n;
      }
    }
  }
#pragma unroll
  for (int m = 0; m < 4; ++m) {
#pragma unroll
    for (int i = 0; i < 4; ++i) {
      float t = lp[m][i];
      t += __shfl_xor(t, 1);
      t += __shfl_xor(t, 2);
      t += __shfl_xor(t, 4);
      t += __shfl_xor(t, 8);                   // sum over the 16 e-lanes
      if (lr == 0) sm_lp[(m * 16 + lq * 4 + i) * 4 + wid] = t;
    }
  }
  __syncthreads();
  if (tid < 64)
    sm_lg[tid] = sm_lp[tid*4+0] + sm_lp[tid*4+1] + sm_lp[tid*4+2] + sm_lp[tid*4+3];
  __syncthreads();

  // ---- chunk-local softmax partials + pooled partial vector ----
  float mx = -1e30f;
  for (int r = 0; r < 64; ++r) mx = fmaxf(mx, sm_lg[r]);   // uniform LDS broadcast
  if (tid < 64) sm_e[tid] = __expf(sm_lg[tid] - mx);
  __syncthreads();

  {
    float o = 0.f;
    for (int r = 0; r < 64; ++r)
      o += sm_e[r] * bf2f(hb[r * 256 + tid]);  // coalesced, L1/L2-hot
    ((float*)(ws + OFF_PO))[blockIdx.x * 256 + tid] = o;
  }
  if (tid == 0) {
    float s = 0.f;
    for (int r = 0; r < 64; ++r) s += sm_e[r];
    ((float*)(ws + OFF_PS))[blockIdx.x] = s;
    ((float*)(ws + OFF_PM))[blockIdx.x] = mx;
  }
}

// K2: combine 32 chunk-partials per batch element (online-softmax merge).
__global__ void k2_combine(const char* __restrict__ ws, float* __restrict__ out) {
  const int b = blockIdx.x;
  const int d = threadIdx.x;
  const float* pm = (const float*)(ws + OFF_PM) + b * 32;
  const float* ps = (const float*)(ws + OFF_PS) + b * 32;
  const float* po = (const float*)(ws + OFF_PO) + (size_t)b * 32 * 256;
  float mx = -1e30f;
  for (int c = 0; c < 32; ++c) mx = fmaxf(mx, pm[c]);
  float num = 0.f, den = 0.f;
  for (int c = 0; c < 32; ++c) {
    const float al = __expf(pm[c] - mx);
    den += al * ps[c];
    num += al * po[c * 256 + d];
  }
  out[b * 256 + d] = num / den;
}

extern "C" void kernel_launch(void* const* d_in, const int* in_sizes, int n_in,
                              void* d_out, int out_size, void* d_ws, size_t ws_size,
                              hipStream_t stream) {
  const float* x     = (const float*)d_in[0];
  const float* gamma = (const float*)d_in[1];
  const float* beta  = (const float*)d_in[2];
  const float* Wp    = (const float*)d_in[3];
  const float* bproj = (const float*)d_in[4];
  const float* W1    = (const float*)d_in[5];
  const float* b1    = (const float*)d_in[6];
  const float* W2    = (const float*)d_in[7];
  // d_in[8] = b2 scalar: softmax is shift-invariant -> drops out exactly.
  char* ws = (char*)d_ws;   // needs ~68 MB
  float* out = (float*)d_out;

  k0_prep   <<<dim3(64),   dim3(256), 0, stream>>>(Wp, gamma, beta, W1, ws);
  k0_reduce <<<dim3(1),    dim3(256), 0, stream>>>(bproj, ws);
  k1a_proj  <<<dim3(2048), dim3(256), 0, stream>>>(x, ws);
  k1b_mlp   <<<dim3(2048), dim3(256), 0, stream>>>(b1, W2, ws);
  k2_combine<<<dim3(64),   dim3(256), 0, stream>>>(ws, out);
}

// Round 6
// 184.561 us; speedup vs baseline: 1.1571x; 1.1571x over previous
//
#include <hip/hip_runtime.h>

#define LN_EPS 1e-5f

typedef __attribute__((ext_vector_type(8))) short s8vec;   // 8 bf16 (MFMA A/B frag)
typedef __attribute__((ext_vector_type(4))) float f4vec;   // MFMA C/D frag

// ---- workspace layout (bytes); total ~2.74 MB ----
#define OFF_WPT   0u         // gamma-folded W_projT, PRE-SWIZZLED [24 chunks][256 n][64 B]
#define OFF_W1T   393216u    // W1T, PRE-SWIZZLED [4 chunks][256 e][128 B]
#define OFF_U     524288u    // u[256] f32 : sum_k gamma_k W[k][d]
#define OFF_C     525312u    // c[256] f32 : sum_k beta_k W[k][d] + b_proj[d]
#define OFF_UPART 526336u    // 48*256 f32 partials
#define OFF_VPART 575488u
#define OFF_PM    624640u    // per-chunk softmax max   [2048] f32
#define OFF_PS    632832u    // per-chunk softmax denom [2048] f32
#define OFF_PO    641024u    // per-chunk weighted sums [2048][256] f32

#define BAR()     asm volatile("s_barrier" ::: "memory")
#define WAIT_V2() asm volatile("s_waitcnt vmcnt(2) lgkmcnt(0)" ::: "memory")
#define WAIT_V0() asm volatile("s_waitcnt vmcnt(0) lgkmcnt(0)" ::: "memory")
#define WAIT_L0() asm volatile("s_waitcnt lgkmcnt(0)" ::: "memory")
// Pin issue order so counted vmcnt is valid: gll16s must stay the OLDEST
// outstanding vmem ops (round-3 lesson; race otherwise).
#define ORDER_FENCE() do { asm volatile("" ::: "memory"); \
                           __builtin_amdgcn_sched_barrier(0); } while (0)

__device__ __forceinline__ unsigned short f2bf(float f) {  // RNE fp32->bf16 (finite inputs)
  unsigned int u = __float_as_uint(f);
  u += 0x7fffu + ((u >> 16) & 1u);
  return (unsigned short)(u >> 16);
}
__device__ __forceinline__ float bf2f(unsigned short h) {
  return __uint_as_float(((unsigned int)h) << 16);
}
__device__ __forceinline__ void gll16(const void* g, void* l) {  // async global->LDS, 16 B/lane
  __builtin_amdgcn_global_load_lds(
      (const __attribute__((address_space(1))) unsigned int*)g,
      (__attribute__((address_space(3))) unsigned int*)l, 16, 0, 0);
}

// K0: fold gamma into W_proj, transpose, store PRE-INVERSE-SWIZZLED.
// W'T: 24 chunks of [256 n][64 B], XOR (n&3)<<4 within the 64 B row.
// W1T: 4 chunks of [256 e][128 B], XOR (e&7)<<4 within the 128 B row (round-4).
__global__ void k0_prep(const float* __restrict__ Wp,
                        const float* __restrict__ gamma,
                        const float* __restrict__ beta,
                        const float* __restrict__ W1,
                        char* __restrict__ ws) {
  const int blk = blockIdx.x;
  const int n = threadIdx.x;
  if (blk < 48) {
    unsigned short* wpt = (unsigned short*)(ws + OFF_WPT);
    const int sw = (n & 3) << 4;
    const int k0 = blk * 16;
    float up = 0.f, vp = 0.f;
#pragma unroll
    for (int j = 0; j < 16; ++j) {
      const int k = k0 + j;
      const float w = Wp[k * 256 + n];          // coalesced across n
      const float wpv = gamma[k] * w;
      up += wpv;
      vp += beta[k] * w;
      const int c = k >> 5, kc = k & 31;
      wpt[c * 8192 + n * 32 + ((((kc * 2) ^ sw)) >> 1)] = f2bf(wpv);
    }
    ((float*)(ws + OFF_UPART))[blk * 256 + n] = up;
    ((float*)(ws + OFF_VPART))[blk * 256 + n] = vp;
  } else {
    unsigned short* w1t = (unsigned short*)(ws + OFF_W1T);
    const int sw = (n & 7) << 4;
    const int d0 = (blk - 48) * 16;
#pragma unroll
    for (int j = 0; j < 16; ++j) {
      const int d = d0 + j;
      const int c = d >> 6, dc = d & 63;
      w1t[c * 16384 + n * 64 + ((((dc * 2) ^ sw)) >> 1)] = f2bf(W1[d * 256 + n]);
    }
  }
}

__global__ void k0_reduce(const float* __restrict__ bproj, char* __restrict__ ws) {
  const int n = threadIdx.x;
  const float* upart = (const float*)(ws + OFF_UPART);
  const float* vpart = (const float*)(ws + OFF_VPART);
  float u = 0.f, v = 0.f;
  for (int i = 0; i < 48; ++i) {
    u += upart[i * 256 + n];
    v += vpart[i * 256 + n];
  }
  ((float*)(ws + OFF_U))[n] = u;
  ((float*)(ws + OFF_C))[n] = v + bproj[n];
}

// K1: per block = 64 rows of one batch element. 256 threads, ~78 KB LDS ->
// 2 blocks/CU. Phase 1 = true 2-phase double-buffered pipeline: stage chunk
// t+1 while MFMA consumes chunk t; one barrier + one counted wait per iter.
__global__ __launch_bounds__(256, 2)
void k1_main(const float* __restrict__ x,
             const float* __restrict__ b1,
             const float* __restrict__ W2,
             char* __restrict__ ws) {
  __shared__ __align__(16) char sm_h[32768];   // h tile bf16 [64][256], XOR (r&7)<<4
  __shared__ __align__(16) char sm_b[32768];   // ph1: 2 x 16KB dbuf; ph2: 32KB W1T chunk
  __shared__ __align__(16) char sm_a[8192];    // ph1: 2 x 4KB A dbuf
  __shared__ float sm_u[256], sm_c[256], sm_b1[256], sm_w2[256];
  __shared__ float sm_mu[64], sm_inv[64];
  __shared__ float sm_lp[64 * 4];
  __shared__ float sm_lg[64];
  __shared__ float sm_e[64];

  const int tid  = threadIdx.x;
  const int lane = tid & 63;
  const int wid  = tid >> 6;     // wave col 0..3 (64 N-cols each; waves share all 64 M-rows)
  const int lr = lane & 15;
  const int lq = lane >> 4;

  sm_u[tid]  = ((const float*)(ws + OFF_U))[tid];
  sm_c[tid]  = ((const float*)(ws + OFF_C))[tid];
  sm_b1[tid] = b1[tid];
  sm_w2[tid] = W2[tid];

  const int arow = tid >> 2;     // staging A: 4 threads per row, 8 floats each
  const int aq   = tid & 3;
  const float* xrow = x + (size_t)(blockIdx.x * 64 + arow) * 768 + aq * 8;

  const char* bsrc  = (const char*)ws + OFF_WPT + wid * 4096 + lane * 16;
  const char* b2src = (const char*)ws + OFF_W1T + wid * 8192 + lane * 16;

  const f4vec fz = {0.f, 0.f, 0.f, 0.f};
  f4vec acc[4][4];
#pragma unroll
  for (int m = 0; m < 4; ++m)
#pragma unroll
    for (int n = 0; n < 4; ++n) acc[m][n] = fz;

  float s1 = 0.f, s2 = 0.f;
  float4 xcE[2], xcO[2];                 // ping-pong x chunks (even/odd), 8 floats each
  xcE[0] = *(const float4*)(xrow + 0);  xcE[1] = *(const float4*)(xrow + 4);
  xcO[0] = *(const float4*)(xrow + 32); xcO[1] = *(const float4*)(xrow + 36);

  auto stageB = [&](int t, int p) {      // async copy pre-swizzled W'T chunk -> bbuf[p]
#pragma unroll
    for (int s = 0; s < 4; ++s)
      gll16(bsrc + t * 16384 + s * 1024,
            sm_b + p * 16384 + wid * 4096 + s * 1024 + lane * 16);
  };
  auto packA = [&](const float4 (&xc)[2], int p) {  // sanitize, LN sums, bf16 -> abuf[p]
    float v[8];
    v[0]=xc[0].x; v[1]=xc[0].y; v[2]=xc[0].z; v[3]=xc[0].w;
    v[4]=xc[1].x; v[5]=xc[1].y; v[6]=xc[1].z; v[7]=xc[1].w;
    unsigned int pk[4];
#pragma unroll
    for (int j = 0; j < 8; ++j) {
      float f = v[j];
      if ((__float_as_uint(f) & 0x7f800000u) == 0x7f800000u) f = 0.f;  // nan/inf -> 0
      s1 += f; s2 += f * f;
      const unsigned int hb = f2bf(f);
      if ((j & 1) == 0) pk[j >> 1] = hb; else pk[j >> 1] |= hb << 16;
    }
    *(int4*)(sm_a + p * 4096 + ((arow * 64 + aq * 16) ^ ((arow & 3) << 4))) =
        make_int4((int)pk[0], (int)pk[1], (int)pk[2], (int)pk[3]);
  };
  auto mfmaStep = [&](int p) {           // consume chunk in buf p (K=32, 16 MFMA)
    s8vec af[4], bf[4];
#pragma unroll
    for (int m = 0; m < 4; ++m) {
      const int row = m * 16 + lr;
      af[m] = *(const s8vec*)(sm_a + p * 4096 +
                              ((row * 64 + lq * 16) ^ ((row & 3) << 4)));
    }
#pragma unroll
    for (int n = 0; n < 4; ++n) {
      const int row = wid * 64 + n * 16 + lr;
      bf[n] = *(const s8vec*)(sm_b + p * 16384 +
                              ((row * 64 + lq * 16) ^ ((row & 3) << 4)));
    }
    __builtin_amdgcn_s_setprio(1);
#pragma unroll
    for (int m = 0; m < 4; ++m)
#pragma unroll
      for (int n = 0; n < 4; ++n)
        acc[m][n] = __builtin_amdgcn_mfma_f32_16x16x32_bf16(af[m], bf[n], acc[m][n], 0, 0, 0);
    __builtin_amdgcn_s_setprio(0);
  };

  // ---- prologue: stage chunk 0 ----
  stageB(0, 0); ORDER_FENCE();
  packA(xcE, 0);
  xcE[0] = *(const float4*)(xrow + 64); xcE[1] = *(const float4*)(xrow + 68);  // chunk 2
  WAIT_V2(); BAR();

  // ---- steady state: chunk t in buf (t&1); stage t+1 while MFMA t ----
  for (int t = 0; t < 22; t += 2) {
    stageB(t + 1, 1); ORDER_FENCE();
    packA(xcO, 1);                                        // chunk t+1
    xcO[0] = *(const float4*)(xrow + (t + 3) * 32);       // refill: chunk t+3 (t<=20 -> <=23)
    xcO[1] = *(const float4*)(xrow + (t + 3) * 32 + 4);
    mfmaStep(0);                                          // chunk t
    WAIT_V2(); BAR();

    stageB(t + 2, 0); ORDER_FENCE();
    packA(xcE, 0);                                        // chunk t+2
    if (t + 4 <= 23) {
      xcE[0] = *(const float4*)(xrow + (t + 4) * 32);
      xcE[1] = *(const float4*)(xrow + (t + 4) * 32 + 4);
    }
    mfmaStep(1);                                          // chunk t+1
    if (t + 4 <= 23) WAIT_V2(); else WAIT_V0();
    BAR();
  }
  // tail: processed 0..21, staged/packed 0..22; xcO holds chunk 23
  stageB(23, 1); ORDER_FENCE();
  packA(xcO, 1);
  mfmaStep(0);                                            // chunk 22
  WAIT_V0(); BAR();
  mfmaStep(1);                                            // chunk 23
  BAR();                                                  // sm_b reads done before W1T staging

  // ---- LN row stats (reduce the 4 staging lanes of each row) ----
  s1 += __shfl_xor(s1, 1); s1 += __shfl_xor(s1, 2);
  s2 += __shfl_xor(s2, 1); s2 += __shfl_xor(s2, 2);
  if (aq == 0) {
    const float mu = s1 * (1.f / 768.f);
    float var = s2 * (1.f / 768.f) - mu * mu;
    var = fmaxf(var, 0.f);
    sm_mu[arow]  = mu;
    sm_inv[arow] = rsqrtf(var + LN_EPS);
  }
  // issue phase-2 chunk-0 W1T load early: hides L2 latency under h-finalize VALU
#pragma unroll
  for (int s = 0; s < 8; ++s)
    gll16(b2src + s * 1024, sm_b + wid * 8192 + s * 1024 + lane * 16);
  WAIT_L0();                             // sm_mu/sm_inv writes drained (gll still flying)
  BAR();

  // ---- finalize h = inv*(g - mu*u) + c, write bf16 h tile ----
#pragma unroll
  for (int m = 0; m < 4; ++m) {
#pragma unroll
    for (int i = 0; i < 4; ++i) {
      const int rl = m * 16 + lq * 4 + i;
      const float mu  = sm_mu[rl];
      const float inv = sm_inv[rl];
      const int sw = (rl & 7) << 4;
#pragma unroll
      for (int n = 0; n < 4; ++n) {
        const int cd = wid * 64 + n * 16 + lr;
        const float h = inv * (acc[m][n][i] - mu * sm_u[cd]) + sm_c[cd];
        *(unsigned short*)(sm_h + ((rl * 512 + cd * 2) ^ sw)) = f2bf(h);
      }
    }
  }
  WAIT_V0();                             // W1T chunk 0 landed + sm_h writes drained
  BAR();

  // ---- phase 2: a = tanh(h@W1 + b1), logits = a.W2 ----
  f4vec acc2[4][4];
#pragma unroll
  for (int m = 0; m < 4; ++m)
#pragma unroll
    for (int n = 0; n < 4; ++n) acc2[m][n] = fz;

  for (int c = 0; c < 4; ++c) {
    // read ALL fragments for chunk c into regs first, so the next B chunk's
    // global_load_lds can overlap the MFMA burst (single sm_b buffer).
    s8vec af[2][4], bfv[2][4];
#pragma unroll
    for (int ks = 0; ks < 2; ++ks) {
      const int kh = (c * 64 + ks * 32 + lq * 8) * 2;  // byte col in h row (512 B)
      const int kb = (ks * 32 + lq * 8) * 2;           // byte col in B row (128 B)
#pragma unroll
      for (int m = 0; m < 4; ++m) {
        const int row = m * 16 + lr;
        af[ks][m] = *(const s8vec*)(sm_h + ((row * 512 + kh) ^ ((row & 7) << 4)));
      }
#pragma unroll
      for (int n = 0; n < 4; ++n) {
        const int row = wid * 64 + n * 16 + lr;
        bfv[ks][n] = *(const s8vec*)(sm_b + ((row * 128 + kb) ^ ((row & 7) << 4)));
      }
    }
    WAIT_L0();                           // frags in regs; sm_b free to overwrite
    BAR();
    if (c < 3) {
#pragma unroll
      for (int s = 0; s < 8; ++s)
        gll16(b2src + (c + 1) * 32768 + s * 1024,
              sm_b + wid * 8192 + s * 1024 + lane * 16);
    }
    __builtin_amdgcn_s_setprio(1);
#pragma unroll
    for (int ks = 0; ks < 2; ++ks)
#pragma unroll
      for (int m = 0; m < 4; ++m)
#pragma unroll
        for (int n = 0; n < 4; ++n)
          acc2[m][n] = __builtin_amdgcn_mfma_f32_16x16x32_bf16(af[ks][m], bfv[ks][n], acc2[m][n], 0, 0, 0);
    __builtin_amdgcn_s_setprio(0);
    if (c < 3) WAIT_V0();                // next B chunk landed
    BAR();
  }

  float lp[4][4];
#pragma unroll
  for (int m = 0; m < 4; ++m)
#pragma unroll
    for (int i = 0; i < 4; ++i) lp[m][i] = 0.f;

#pragma unroll
  for (int m = 0; m < 4; ++m) {
#pragma unroll
    for (int n = 0; n < 4; ++n) {
      const int cd = wid * 64 + n * 16 + lr;
      const float b1v = sm_b1[cd];
      const float w2v = sm_w2[cd];
#pragma unroll
      for (int i = 0; i < 4; ++i) {
        float z = acc2[m][n][i] + b1v;
        z = fminf(fmaxf(z, -15.f), 15.f);
        const float e2 = __expf(2.f * z);
        const float a = (e2 - 1.f) / (e2 + 1.f);   // tanh
        lp[m][i] += a * w2v;
      }
    }
  }
#pragma unroll
  for (int m = 0; m < 4; ++m) {
#pragma unroll
    for (int i = 0; i < 4; ++i) {
      float t = lp[m][i];
      t += __shfl_xor(t, 1);
      t += __shfl_xor(t, 2);
      t += __shfl_xor(t, 4);
      t += __shfl_xor(t, 8);                      // sum over the 16 col-lanes
      if (lr == 0) sm_lp[(m * 16 + lq * 4 + i) * 4 + wid] = t;
    }
  }
  __syncthreads();
  if (tid < 64)
    sm_lg[tid] = sm_lp[tid*4+0] + sm_lp[tid*4+1] + sm_lp[tid*4+2] + sm_lp[tid*4+3];
  __syncthreads();

  // ---- phase 3: chunk-local softmax partials + pooled partial vector ----
  float mx = -1e30f;
  for (int r = 0; r < 64; ++r) mx = fmaxf(mx, sm_lg[r]);   // LDS broadcast, uniform
  if (tid < 64) sm_e[tid] = __expf(sm_lg[tid] - mx);
  __syncthreads();

  {
    const int d = tid;
    float o = 0.f;
    for (int r = 0; r < 64; ++r) {
      const float ev = sm_e[r];
      const unsigned short hb =
          *(const unsigned short*)(sm_h + ((r * 512 + d * 2) ^ ((r & 7) << 4)));
      o += ev * bf2f(hb);
    }
    ((float*)(ws + OFF_PO))[blockIdx.x * 256 + d] = o;
  }
  if (tid == 0) {
    float s = 0.f;
    for (int r = 0; r < 64; ++r) s += sm_e[r];
    ((float*)(ws + OFF_PS))[blockIdx.x] = s;
    ((float*)(ws + OFF_PM))[blockIdx.x] = mx;
  }
}

// K2: combine 32 chunk-partials per batch element (online-softmax merge).
__global__ void k2_combine(const char* __restrict__ ws, float* __restrict__ out) {
  const int b = blockIdx.x;
  const int d = threadIdx.x;
  const float* pm = (const float*)(ws + OFF_PM) + b * 32;
  const float* ps = (const float*)(ws + OFF_PS) + b * 32;
  const float* po = (const float*)(ws + OFF_PO) + (size_t)b * 32 * 256;
  float mx = -1e30f;
  for (int c = 0; c < 32; ++c) mx = fmaxf(mx, pm[c]);
  float num = 0.f, den = 0.f;
  for (int c = 0; c < 32; ++c) {
    const float al = __expf(pm[c] - mx);
    den += al * ps[c];
    num += al * po[c * 256 + d];
  }
  out[b * 256 + d] = num / den;
}

extern "C" void kernel_launch(void* const* d_in, const int* in_sizes, int n_in,
                              void* d_out, int out_size, void* d_ws, size_t ws_size,
                              hipStream_t stream) {
  const float* x     = (const float*)d_in[0];
  const float* gamma = (const float*)d_in[1];
  const float* beta  = (const float*)d_in[2];
  const float* Wp    = (const float*)d_in[3];
  const float* bproj = (const float*)d_in[4];
  const float* W1    = (const float*)d_in[5];
  const float* b1    = (const float*)d_in[6];
  const float* W2    = (const float*)d_in[7];
  // d_in[8] = b2 scalar: softmax is shift-invariant -> drops out exactly.
  char* ws = (char*)d_ws;   // needs ~2.74 MB
  float* out = (float*)d_out;

  k0_prep   <<<dim3(64),   dim3(256), 0, stream>>>(Wp, gamma, beta, W1, ws);
  k0_reduce <<<dim3(1),    dim3(256), 0, stream>>>(bproj, ws);
  k1_main   <<<dim3(2048), dim3(256), 0, stream>>>(x, b1, W2, ws);
  k2_combine<<<dim3(64),   dim3(256), 0, stream>>>(ws, out);
}